// Round 8
// baseline (190.954 us; speedup 1.0000x reference)
//
#include <hip/hip_runtime.h>
#include <hip/hip_fp16.h>

// B=64, I=2048, D=8, O=32, K=16.  e-layout o-major: e = o*16 + k.
//
// Round-7 discovery: wave64 waves/SIMD = ~256/VGPR on gfx950 (VGPR=64 -> 4
// waves/SIMD cap regardless of grid; VGPR=32 -> 8). W needs 64 f32 regs, so
// occupancy is capped at 4 waves/SIMD -> pivot to VALU-count reduction:
// v_dot2_f32_f16 halves the 64-FMA u_hat core (W packed fp16 pairs along d,
// 32 VGPRs; x staged pre-packed fp16 in LDS; ACCUMULATION STAYS F32 -> only
// x/W quantization ~5e-4 rel). Softmax (DPP+swizzle), fp16 redh/part, fold,
// reduce: unchanged from round 7 (proven).
//
// grid 1024 = (qh = bx>>8: b-quarter, 16 b's) x (ch = bx&255: 8-i chunk).
// wave w = i-slot; lane: o = l&31, kk = l>>5.

typedef _Float16 hf2 __attribute__((ext_vector_type(2)));

struct __align__(16) H8 { __half2 a, b, c, d; };
struct __align__(8)  H4 { __half2 a, b; };

__device__ __forceinline__ float dot2(hf2 a, hf2 b, float c) {
#if __has_builtin(__builtin_amdgcn_fdot2)
    return __builtin_amdgcn_fdot2(a, b, c, false);   // v_dot2_f32_f16
#else
    return fmaf((float)a.x, (float)b.x, fmaf((float)a.y, (float)b.y, c));
#endif
}

template<int CTRL>
__device__ __forceinline__ float dppadd(float v) {   // v + dpp_perm(v), VALU-only
    return v + __int_as_float(__builtin_amdgcn_update_dpp(
        0, __float_as_int(v), CTRL, 0xF, 0xF, true));
}

template<int PASS0>
__global__ __launch_bounds__(512, 4)   // budget 64 VGPR: no spill (r4/r7-proven)
void pass_kernel(const float* __restrict__ x,    // [64][2048][8]
                 const float* __restrict__ W,    // [2048][32][8][16]
                 const float* __restrict__ vin,  // [64][512] f32, o-major
                 __half* __restrict__ part)      // [64][256][512] fp16
{
    __shared__ __align__(16) hf2    x_ldsh[16][8][4];  //  2 KB: [bl][i][d-pair]
    __shared__ __align__(16) __half redh[2][16][512];  // 32 KB: [par][slot*2+bq][e]

    const int t  = threadIdx.x;
    const int w  = t >> 6;
    const int l  = t & 63;
    const int o  = l & 31;
    const int kk = l >> 5;
    const int bx = blockIdx.x;
    const int ch = bx & 255;
    const int qh = bx >> 8;          // b-quarter: b in [qh*16, qh*16+16)
    const int i  = ch * 8 + w;

    // ---- W[i][o][d][kk-half] -> 32 regs of packed fp16 d-pairs, PINNED -----
    float Whf[4][8];                 // bit-packed hf2: (W[2d2][j], W[2d2+1][j])
    {
        const float* wp = W + (size_t)(i * 32 + o) * 128 + kk * 8;
        #pragma unroll
        for (int d2 = 0; d2 < 4; ++d2) {
            float4 a0 = *(const float4*)(wp + (2 * d2) * 16);
            float4 a1 = *(const float4*)(wp + (2 * d2) * 16 + 4);
            float4 b0 = *(const float4*)(wp + (2 * d2 + 1) * 16);
            float4 b1 = *(const float4*)(wp + (2 * d2 + 1) * 16 + 4);
            float r0[8] = {a0.x, a0.y, a0.z, a0.w, a1.x, a1.y, a1.z, a1.w};
            float r1[8] = {b0.x, b0.y, b0.z, b0.w, b1.x, b1.y, b1.z, b1.w};
            #pragma unroll
            for (int j = 0; j < 8; ++j) {
                hf2 p; p.x = (_Float16)r0[j]; p.y = (_Float16)r1[j];
                Whf[d2][j] = __builtin_bit_cast(float, p);
            }
        }
        #pragma unroll
        for (int d2 = 0; d2 < 4; ++d2)
            #pragma unroll
            for (int j = 0; j < 8; ++j)
                asm volatile("" : "+v"(Whf[d2][j]));   // force VGPR residency
    }
    // ---- stage x packed fp16: 512 hf2, one per thread ----------------------
    {
        const int bl = t >> 5, wv = (t >> 2) & 7, d2 = t & 3;
        const float2 xx = *(const float2*)(
            x + (size_t)(qh * 16 + bl) * 16384 + (size_t)(ch * 8 + wv) * 8 + 2 * d2);
        hf2 p; p.x = (_Float16)xx.x; p.y = (_Float16)xx.y;
        x_ldsh[bl][wv][d2] = p;
    }

    #pragma unroll 2
    for (int g = 0; g < 8; ++g) {        // 2 b's per group, 8 groups
        __syncthreads();                 // redh[g&1] free; g=0: x_ldsh ready

        // ---- fold(g-1): sum 8 i-slots of redh[(g-1)&1], write part (fp16) --
        if (g && t < 256) {
            const int bqf = t >> 7;
            const int hx  = (t & 127) * 4;           // half index in [0,512)
            const __half* rp = &redh[(g - 1) & 1][0][0];
            float a0 = 0.f, a1 = 0.f, a2 = 0.f, a3 = 0.f;
            #pragma unroll
            for (int s = 0; s < 8; ++s) {
                H4 v = *(const H4*)(rp + (s * 2 + bqf) * 512 + hx);
                float2 f0 = __half22float2(v.a), f1 = __half22float2(v.b);
                a0 += f0.x; a1 += f0.y; a2 += f1.x; a3 += f1.y;
            }
            const int b = qh * 16 + (g - 1) * 2 + bqf;
            H4 o4;
            o4.a = __floats2half2_rn(a0, a1);
            o4.b = __floats2half2_rn(a2, a3);
            *(H4*)(part + ((size_t)b * 256 + ch) * 512 + hx) = o4;
        }

        // ---- compute(g) -> redh[g&1] --------------------------------------
        #pragma unroll
        for (int bq = 0; bq < 2; ++bq) {
            const int bl = g * 2 + bq;
            float4 va, vb;
            if (!PASS0) {                // issue v loads first (L1/L2 latency)
                const float* vp = vin + (size_t)(qh * 16 + bl) * 512 + o * 16 + kk * 8;
                va = *(const float4*)vp;
                vb = *(const float4*)(vp + 4);
            }
            // x for this (b, i): 4 packed d-pairs, one 16B broadcast read
            const hf2* xp = &x_ldsh[bl][w][0];
            hf2 xa0 = xp[0], xa1 = xp[1], xa2 = xp[2], xa3 = xp[3];
            float uh[8];
            #pragma unroll
            for (int j = 0; j < 8; ++j) uh[j] = 0.f;
            #pragma unroll
            for (int j = 0; j < 8; ++j) {
                uh[j] = dot2(xa0, __builtin_bit_cast(hf2, Whf[0][j]), uh[j]);
                uh[j] = dot2(xa1, __builtin_bit_cast(hf2, Whf[1][j]), uh[j]);
                uh[j] = dot2(xa2, __builtin_bit_cast(hf2, Whf[2][j]), uh[j]);
                uh[j] = dot2(xa3, __builtin_bit_cast(hf2, Whf[3][j]), uh[j]);
            }
            float c;
            if (PASS0) {
                c = 0.03125f;            // softmax of zeros
            } else {
                float logit = uh[0] * va.x;
                logit = fmaf(uh[1], va.y, logit);
                logit = fmaf(uh[2], va.z, logit);
                logit = fmaf(uh[3], va.w, logit);
                logit = fmaf(uh[4], vb.x, logit);
                logit = fmaf(uh[5], vb.y, logit);
                logit = fmaf(uh[6], vb.z, logit);
                logit = fmaf(uh[7], vb.w, logit);
                logit += __shfl_xor(logit, 32, 64);   // combine k-halves (1 DS)
                float ex = __expf(logit);             // |logit| small: no max
                float sm = ex;                        // o-sum: 4 DPP + xor16
                sm = dppadd<0xB1>(sm);                // quad_perm xor1
                sm = dppadd<0x4E>(sm);                // quad_perm xor2
                sm = dppadd<0x124>(sm);               // row_ror:4
                sm = dppadd<0x128>(sm);               // row_ror:8
                sm += __int_as_float(__builtin_amdgcn_ds_swizzle(
                          __float_as_int(sm), 0x401F));   // xor16 within 32
                c = __fdividef(ex, sm);
            }
            H8 pk;
            pk.a = __floats2half2_rn(c * uh[0], c * uh[1]);
            pk.b = __floats2half2_rn(c * uh[2], c * uh[3]);
            pk.c = __floats2half2_rn(c * uh[4], c * uh[5]);
            pk.d = __floats2half2_rn(c * uh[6], c * uh[7]);
            *(H8*)&redh[g & 1][w * 2 + bq][o * 16 + kk * 8] = pk;   // 1 b128
        }
    }
    __syncthreads();
    if (t < 256) {   // ---- epilogue fold(g=7) from redh[1] ------------------
        const int bqf = t >> 7;
        const int hx  = (t & 127) * 4;
        const __half* rp = &redh[1][0][0];
        float a0 = 0.f, a1 = 0.f, a2 = 0.f, a3 = 0.f;
        #pragma unroll
        for (int s = 0; s < 8; ++s) {
            H4 v = *(const H4*)(rp + (s * 2 + bqf) * 512 + hx);
            float2 f0 = __half22float2(v.a), f1 = __half22float2(v.b);
            a0 += f0.x; a1 += f0.y; a2 += f1.x; a3 += f1.y;
        }
        const int b = qh * 16 + 14 + bqf;
        H4 o4;
        o4.a = __floats2half2_rn(a0, a1);
        o4.b = __floats2half2_rn(a2, a3);
        *(H4*)(part + ((size_t)b * 256 + ch) * 512 + hx) = o4;
    }
}

// ---------------------------------------------------------------------------
// Reduce (round-4/7 proven): grid 512 = (b = bx>>3) x (q = bx&7: 64-e slice =
// 4 complete o's). 1024 threads: f = t&7 (16B = 8 halves), c0 = t>>3 (chunk
// row in [0,128)); 2 x 16B loads/thread, f32 accumulate, 3-stage LDS fold,
// squash tail. PHASE 0: vsum=v; 1: vsum+=v; 2: out[b][o][k]=v.
// ---------------------------------------------------------------------------
template<int PHASE>
__global__ __launch_bounds__(1024)
void reduce_kernel(const __half* __restrict__ part,
                   float* __restrict__ vsum,
                   float* __restrict__ out)
{
    __shared__ __align__(16) float sA[128][64];   // 32 KB
    __shared__ __align__(16) float sB[16][64];    //  4 KB
    const int bx = blockIdx.x;
    const int b  = bx >> 3;
    const int q  = bx & 7;
    const int t  = threadIdx.x;
    const int f  = t & 7;
    const int c0 = t >> 3;                        // chunk row in [0,128)

    const __half* p0 = part + ((size_t)b * 256 + c0) * 512 + q * 64 + f * 8;
    float acc[8] = {0.f, 0.f, 0.f, 0.f, 0.f, 0.f, 0.f, 0.f};
    #pragma unroll
    for (int rr = 0; rr < 2; ++rr) {              // rows c0, c0+128
        H8 v = *(const H8*)(p0 + (size_t)rr * 128 * 512);
        float2 f0 = __half22float2(v.a), f1 = __half22float2(v.b),
               f2 = __half22float2(v.c), f3 = __half22float2(v.d);
        acc[0] += f0.x; acc[1] += f0.y; acc[2] += f1.x; acc[3] += f1.y;
        acc[4] += f2.x; acc[5] += f2.y; acc[6] += f3.x; acc[7] += f3.y;
    }
    *(float4*)&sA[c0][f * 8]     = make_float4(acc[0], acc[1], acc[2], acc[3]);
    *(float4*)&sA[c0][f * 8 + 4] = make_float4(acc[4], acc[5], acc[6], acc[7]);
    __syncthreads();

    {                                             // 128 rows -> 16
        const int e = t & 63, r4 = t >> 6;        // r4 in [0,16)
        float sb = 0.f;
        #pragma unroll
        for (int k2 = 0; k2 < 8; ++k2) sb += sA[r4 + k2 * 16][e];
        sB[r4][e] = sb;
    }
    __syncthreads();

    if (t < 64) {                                 // one wave: 16 rows, squash
        float s1 = 0.f;
        #pragma unroll
        for (int r = 0; r < 16; ++r) s1 += sB[r][t];
        float sq = s1 * s1;
        #pragma unroll
        for (int off = 8; off >= 1; off >>= 1)
            sq += __shfl_xor(sq, off, 16);        // sum over 16 k within o
        float v = (sq / (1.f + sq) * rsqrtf(sq + 1e-7f)) * s1;
        const size_t idx = (size_t)b * 512 + q * 64 + t;
        if (PHASE == 2)      out[idx]   = v;      // e = o*16+k == [b][o][k]
        else if (PHASE == 1) vsum[idx] += v;
        else                 vsum[idx]  = v;
    }
}

// ---------------------------------------------------------------------------
extern "C" void kernel_launch(void* const* d_in, const int* in_sizes, int n_in,
                              void* d_out, int out_size, void* d_ws, size_t ws_size,
                              hipStream_t stream)
{
    const float* x = (const float*)d_in[0];
    const float* W = (const float*)d_in[1];
    float* out = (float*)d_out;
    char* ws = (char*)d_ws;

    const size_t partB = (size_t)64 * 256 * 512 * 2;   // 16 MB (fp16)
    const size_t vsumB = (size_t)64 * 512 * 4;         // 128 KB
    if (ws_size < partB + vsumB) return;               // never taken

    __half* part = (__half*)ws;
    float*  vsum = (float*)(ws + partB);

    // round 0: c uniform -> v0; vsum = v0
    pass_kernel<1><<<1024, 512, 0, stream>>>(x, W, vsum, part);
    reduce_kernel<0><<<512, 1024, 0, stream>>>(part, vsum, out);
    // round 1: logits = u_hat . v0 -> v1; vsum = v0 + v1
    pass_kernel<0><<<1024, 512, 0, stream>>>(x, W, vsum, part);
    reduce_kernel<1><<<512, 1024, 0, stream>>>(part, vsum, out);
    // round 2: logits = u_hat . (v0+v1) -> v2 = output
    pass_kernel<0><<<1024, 512, 0, stream>>>(x, W, vsum, part);
    reduce_kernel<2><<<512, 1024, 0, stream>>>(part, vsum, out);
}

// Round 10
// 178.934 us; speedup vs baseline: 1.0672x; 1.0672x over previous
//
#include <hip/hip_runtime.h>
#include <hip/hip_fp16.h>

// B=64, I=2048, D=8, O=32, K=16.  e-layout o-major: e = o*16 + k.
//
// Round-8 postmortem: PASS0 (no softmax) == softmax pass == 45.7us, and
// -30% VALU (fdot2) changed nothing -> the invariant is the W PREAMBLE:
// 128 MB/pass of L2/L3 traffic issued as 16 scattered 16B loads/thread
// (stride 64B: 8x request inflation), poorly hidden at ~3 waves/SIMD.
// Fix: one-time prep_kernel packs W -> fp16 d-pairs in a wave-contiguous
// layout W16[i][j][lane(kk,o)][d2]; pass preamble = 8 float4 loads, each a
// fully-coalesced 1KB wave access. Pass body/fold/reduce = round 8 verbatim.
// (Round 9 was an infra flake - container failed twice, no counters;
//  identical resubmit per round-1/2 precedent.)
//
// grid 1024 = (qh = bx>>8: b-quarter, 16 b's) x (ch = bx&255: 8-i chunk).
// wave w = i-slot; lane: o = l&31, kk = l>>5.

typedef _Float16 hf2 __attribute__((ext_vector_type(2)));

struct __align__(16) H8 { __half2 a, b, c, d; };
struct __align__(8)  H4 { __half2 a, b; };

__device__ __forceinline__ float dot2(hf2 a, hf2 b, float c) {
#if __has_builtin(__builtin_amdgcn_fdot2)
    return __builtin_amdgcn_fdot2(a, b, c, false);   // v_dot2_f32_f16
#else
    return fmaf((float)a.x, (float)b.x, fmaf((float)a.y, (float)b.y, c));
#endif
}

template<int CTRL>
__device__ __forceinline__ float dppadd(float v) {   // v + dpp_perm(v), VALU-only
    return v + __int_as_float(__builtin_amdgcn_update_dpp(
        0, __float_as_int(v), CTRL, 0xF, 0xF, true));
}

// ---------------------------------------------------------------------------
// prep: W[2048][32][8][16] f32 -> W16[i][j 8][l 64][d2 4] packed hf2 (16 MB).
// W16 float4 index for (i, j, l): i*512 + j*64 + l  (each (i,j) = 1 KB block).
// Whf[d2][j] of pass == component d2 of that float4.
// ---------------------------------------------------------------------------
__global__ __launch_bounds__(512)
void prep_kernel(const float* __restrict__ W, float* __restrict__ W16)
{
    const int ch = blockIdx.x;               // 256 blocks: 8 i's each
    const int t  = threadIdx.x;
    const int is = t >> 6, l = t & 63, o = l & 31, kk = l >> 5;
    const int i  = ch * 8 + is;

    const float* wp = W + (size_t)(i * 32 + o) * 128 + kk * 8;
    float r[8][8];
    #pragma unroll
    for (int d = 0; d < 8; ++d) {
        float4 a = *(const float4*)(wp + d * 16);
        float4 b = *(const float4*)(wp + d * 16 + 4);
        r[d][0] = a.x; r[d][1] = a.y; r[d][2] = a.z; r[d][3] = a.w;
        r[d][4] = b.x; r[d][5] = b.y; r[d][6] = b.z; r[d][7] = b.w;
    }
    float4* dst = (float4*)W16 + (size_t)i * 512 + l;
    #pragma unroll
    for (int j = 0; j < 8; ++j) {
        float o4[4];
        #pragma unroll
        for (int d2 = 0; d2 < 4; ++d2) {
            hf2 p; p.x = (_Float16)r[2 * d2][j]; p.y = (_Float16)r[2 * d2 + 1][j];
            o4[d2] = __builtin_bit_cast(float, p);
        }
        dst[(size_t)j * 64] = make_float4(o4[0], o4[1], o4[2], o4[3]);
    }
}

template<int PASS0>
__global__ __launch_bounds__(512, 4)   // r4/r7/r8-proven: no spill
void pass_kernel(const float* __restrict__ x,     // [64][2048][8]
                 const float* __restrict__ W16,   // packed (see prep)
                 const float* __restrict__ vin,   // [64][512] f32, o-major
                 __half* __restrict__ part)       // [64][256][512] fp16
{
    __shared__ __align__(16) hf2    x_ldsh[16][8][4];  //  2 KB: [bl][i][d-pair]
    __shared__ __align__(16) __half redh[2][16][512];  // 32 KB: [par][slot*2+bq][e]

    const int t  = threadIdx.x;
    const int w  = t >> 6;
    const int l  = t & 63;
    const int o  = l & 31;
    const int kk = l >> 5;
    const int bx = blockIdx.x;
    const int ch = bx & 255;
    const int qh = bx >> 8;          // b-quarter: b in [qh*16, qh*16+16)

    // ---- W16 -> 32 regs of packed fp16 d-pairs: 8 coalesced float4 loads ---
    float Whf[4][8];
    {
        const float4* wp = (const float4*)W16 + (size_t)(ch * 8 + w) * 512 + l;
        #pragma unroll
        for (int j = 0; j < 8; ++j) {
            float4 ld = wp[(size_t)j * 64];     // 1 KB contiguous per wave
            Whf[0][j] = ld.x; Whf[1][j] = ld.y; Whf[2][j] = ld.z; Whf[3][j] = ld.w;
        }
        #pragma unroll
        for (int d2 = 0; d2 < 4; ++d2)
            #pragma unroll
            for (int j = 0; j < 8; ++j)
                asm volatile("" : "+v"(Whf[d2][j]));   // force VGPR residency
    }
    // ---- stage x packed fp16: 512 hf2, one per thread ----------------------
    {
        const int bl = t >> 5, wv = (t >> 2) & 7, d2 = t & 3;
        const float2 xx = *(const float2*)(
            x + (size_t)(qh * 16 + bl) * 16384 + (size_t)(ch * 8 + wv) * 8 + 2 * d2);
        hf2 p; p.x = (_Float16)xx.x; p.y = (_Float16)xx.y;
        x_ldsh[bl][wv][d2] = p;
    }

    #pragma unroll 2
    for (int g = 0; g < 8; ++g) {        // 2 b's per group, 8 groups
        __syncthreads();                 // redh[g&1] free; g=0: x_ldsh ready

        // ---- fold(g-1): sum 8 i-slots of redh[(g-1)&1], write part (fp16) --
        if (g && t < 256) {
            const int bqf = t >> 7;
            const int hx  = (t & 127) * 4;           // half index in [0,512)
            const __half* rp = &redh[(g - 1) & 1][0][0];
            float a0 = 0.f, a1 = 0.f, a2 = 0.f, a3 = 0.f;
            #pragma unroll
            for (int s = 0; s < 8; ++s) {
                H4 v = *(const H4*)(rp + (s * 2 + bqf) * 512 + hx);
                float2 f0 = __half22float2(v.a), f1 = __half22float2(v.b);
                a0 += f0.x; a1 += f0.y; a2 += f1.x; a3 += f1.y;
            }
            const int b = qh * 16 + (g - 1) * 2 + bqf;
            H4 o4;
            o4.a = __floats2half2_rn(a0, a1);
            o4.b = __floats2half2_rn(a2, a3);
            *(H4*)(part + ((size_t)b * 256 + ch) * 512 + hx) = o4;
        }

        // ---- compute(g) -> redh[g&1] --------------------------------------
        #pragma unroll
        for (int bq = 0; bq < 2; ++bq) {
            const int bl = g * 2 + bq;
            float4 va, vb;
            if (!PASS0) {                // issue v loads first (L1/L2 latency)
                const float* vp = vin + (size_t)(qh * 16 + bl) * 512 + o * 16 + kk * 8;
                va = *(const float4*)vp;
                vb = *(const float4*)(vp + 4);
            }
            // x for this (b, i): 4 packed d-pairs, one 16B broadcast read
            const hf2* xp = &x_ldsh[bl][w][0];
            hf2 xa0 = xp[0], xa1 = xp[1], xa2 = xp[2], xa3 = xp[3];
            float uh[8];
            #pragma unroll
            for (int j = 0; j < 8; ++j) uh[j] = 0.f;
            #pragma unroll
            for (int j = 0; j < 8; ++j) {
                uh[j] = dot2(xa0, __builtin_bit_cast(hf2, Whf[0][j]), uh[j]);
                uh[j] = dot2(xa1, __builtin_bit_cast(hf2, Whf[1][j]), uh[j]);
                uh[j] = dot2(xa2, __builtin_bit_cast(hf2, Whf[2][j]), uh[j]);
                uh[j] = dot2(xa3, __builtin_bit_cast(hf2, Whf[3][j]), uh[j]);
            }
            float c;
            if (PASS0) {
                c = 0.03125f;            // softmax of zeros
            } else {
                float logit = uh[0] * va.x;
                logit = fmaf(uh[1], va.y, logit);
                logit = fmaf(uh[2], va.z, logit);
                logit = fmaf(uh[3], va.w, logit);
                logit = fmaf(uh[4], vb.x, logit);
                logit = fmaf(uh[5], vb.y, logit);
                logit = fmaf(uh[6], vb.z, logit);
                logit = fmaf(uh[7], vb.w, logit);
                logit += __shfl_xor(logit, 32, 64);   // combine k-halves (1 DS)
                float ex = __expf(logit);             // |logit| small: no max
                float sm = ex;                        // o-sum: 4 DPP + xor16
                sm = dppadd<0xB1>(sm);                // quad_perm xor1
                sm = dppadd<0x4E>(sm);                // quad_perm xor2
                sm = dppadd<0x124>(sm);               // row_ror:4
                sm = dppadd<0x128>(sm);               // row_ror:8
                sm += __int_as_float(__builtin_amdgcn_ds_swizzle(
                          __float_as_int(sm), 0x401F));   // xor16 within 32
                c = __fdividef(ex, sm);
            }
            H8 pk;
            pk.a = __floats2half2_rn(c * uh[0], c * uh[1]);
            pk.b = __floats2half2_rn(c * uh[2], c * uh[3]);
            pk.c = __floats2half2_rn(c * uh[4], c * uh[5]);
            pk.d = __floats2half2_rn(c * uh[6], c * uh[7]);
            *(H8*)&redh[g & 1][w * 2 + bq][o * 16 + kk * 8] = pk;   // 1 b128
        }
    }
    __syncthreads();
    if (t < 256) {   // ---- epilogue fold(g=7) from redh[1] ------------------
        const int bqf = t >> 7;
        const int hx  = (t & 127) * 4;
        const __half* rp = &redh[1][0][0];
        float a0 = 0.f, a1 = 0.f, a2 = 0.f, a3 = 0.f;
        #pragma unroll
        for (int s = 0; s < 8; ++s) {
            H4 v = *(const H4*)(rp + (s * 2 + bqf) * 512 + hx);
            float2 f0 = __half22float2(v.a), f1 = __half22float2(v.b);
            a0 += f0.x; a1 += f0.y; a2 += f1.x; a3 += f1.y;
        }
        const int b = qh * 16 + 14 + bqf;
        H4 o4;
        o4.a = __floats2half2_rn(a0, a1);
        o4.b = __floats2half2_rn(a2, a3);
        *(H4*)(part + ((size_t)b * 256 + ch) * 512 + hx) = o4;
    }
}

// ---------------------------------------------------------------------------
// Reduce (round-4/7/8 proven, unchanged).
// ---------------------------------------------------------------------------
template<int PHASE>
__global__ __launch_bounds__(1024)
void reduce_kernel(const __half* __restrict__ part,
                   float* __restrict__ vsum,
                   float* __restrict__ out)
{
    __shared__ __align__(16) float sA[128][64];   // 32 KB
    __shared__ __align__(16) float sB[16][64];    //  4 KB
    const int bx = blockIdx.x;
    const int b  = bx >> 3;
    const int q  = bx & 7;
    const int t  = threadIdx.x;
    const int f  = t & 7;
    const int c0 = t >> 3;                        // chunk row in [0,128)

    const __half* p0 = part + ((size_t)b * 256 + c0) * 512 + q * 64 + f * 8;
    float acc[8] = {0.f, 0.f, 0.f, 0.f, 0.f, 0.f, 0.f, 0.f};
    #pragma unroll
    for (int rr = 0; rr < 2; ++rr) {              // rows c0, c0+128
        H8 v = *(const H8*)(p0 + (size_t)rr * 128 * 512);
        float2 f0 = __half22float2(v.a), f1 = __half22float2(v.b),
               f2 = __half22float2(v.c), f3 = __half22float2(v.d);
        acc[0] += f0.x; acc[1] += f0.y; acc[2] += f1.x; acc[3] += f1.y;
        acc[4] += f2.x; acc[5] += f2.y; acc[6] += f3.x; acc[7] += f3.y;
    }
    *(float4*)&sA[c0][f * 8]     = make_float4(acc[0], acc[1], acc[2], acc[3]);
    *(float4*)&sA[c0][f * 8 + 4] = make_float4(acc[4], acc[5], acc[6], acc[7]);
    __syncthreads();

    {                                             // 128 rows -> 16
        const int e = t & 63, r4 = t >> 6;        // r4 in [0,16)
        float sb = 0.f;
        #pragma unroll
        for (int k2 = 0; k2 < 8; ++k2) sb += sA[r4 + k2 * 16][e];
        sB[r4][e] = sb;
    }
    __syncthreads();

    if (t < 64) {                                 // one wave: 16 rows, squash
        float s1 = 0.f;
        #pragma unroll
        for (int r = 0; r < 16; ++r) s1 += sB[r][t];
        float sq = s1 * s1;
        #pragma unroll
        for (int off = 8; off >= 1; off >>= 1)
            sq += __shfl_xor(sq, off, 16);        // sum over 16 k within o
        float v = (sq / (1.f + sq) * rsqrtf(sq + 1e-7f)) * s1;
        const size_t idx = (size_t)b * 512 + q * 64 + t;
        if (PHASE == 2)      out[idx]   = v;      // e = o*16+k == [b][o][k]
        else if (PHASE == 1) vsum[idx] += v;
        else                 vsum[idx]  = v;
    }
}

// ---------------------------------------------------------------------------
extern "C" void kernel_launch(void* const* d_in, const int* in_sizes, int n_in,
                              void* d_out, int out_size, void* d_ws, size_t ws_size,
                              hipStream_t stream)
{
    const float* x = (const float*)d_in[0];
    const float* W = (const float*)d_in[1];
    float* out = (float*)d_out;
    char* ws = (char*)d_ws;

    const size_t partB = (size_t)64 * 256 * 512 * 2;        // 16 MB (fp16)
    const size_t vsumB = (size_t)64 * 512 * 4;              // 128 KB
    const size_t w16B  = (size_t)2048 * 32 * 8 * 16 * 2;    // 16 MB (fp16)
    if (ws_size < partB + vsumB + w16B) return;             // = rounds 0-3 total

    __half* part = (__half*)ws;
    float*  vsum = (float*)(ws + partB);
    float*  W16  = (float*)(ws + partB + vsumB);

    // one-time W repack (must rerun every launch: ws may be re-poisoned)
    prep_kernel<<<256, 512, 0, stream>>>(W, W16);

    // round 0: c uniform -> v0; vsum = v0
    pass_kernel<1><<<1024, 512, 0, stream>>>(x, W16, vsum, part);
    reduce_kernel<0><<<512, 1024, 0, stream>>>(part, vsum, out);
    // round 1: logits = u_hat . v0 -> v1; vsum = v0 + v1
    pass_kernel<0><<<1024, 512, 0, stream>>>(x, W16, vsum, part);
    reduce_kernel<1><<<512, 1024, 0, stream>>>(part, vsum, out);
    // round 2: logits = u_hat . (v0+v1) -> v2 = output
    pass_kernel<0><<<1024, 512, 0, stream>>>(x, W16, vsum, part);
    reduce_kernel<2><<<512, 1024, 0, stream>>>(part, vsum, out);
}

// Round 11
// 176.520 us; speedup vs baseline: 1.0818x; 1.0137x over previous
//
#include <hip/hip_runtime.h>
#include <hip/hip_fp16.h>

// B=64, I=2048, D=8, O=32, K=16.  e-layout o-major: e = o*16 + k.
//
// Round-10 postmortem: W16 repack -> 179us; pass ~41us, latency-bound.
// Occupancy model (r6/r7/r8 evidence): waves/SIMD = 256/ceil8(VGPR), blocks
// are 2-waves/SIMD units -> VGPR=44 gives capacity 5 -> only 2 blocks/CU,
// SAME as VGPR=64 (r8's null explained). 3 blocks/CU needs VGPR <= 40.
// This round: vsum stored fp16 -> early-issued v tile is 4 VGPRs (not 8)
// across the dot2 loop; __launch_bounds__(512,6) (budget 42, gentle).
// Everything else = round 10 verbatim (prep/W16, fold, reduce structure).
//
// grid 1024 = (qh = bx>>8: b-quarter, 16 b's) x (ch = bx&255: 8-i chunk).
// wave w = i-slot; lane: o = l&31, kk = l>>5.

typedef _Float16 hf2 __attribute__((ext_vector_type(2)));

struct __align__(16) H8 { __half2 a, b, c, d; };
struct __align__(8)  H4 { __half2 a, b; };

__device__ __forceinline__ float dot2(hf2 a, hf2 b, float c) {
#if __has_builtin(__builtin_amdgcn_fdot2)
    return __builtin_amdgcn_fdot2(a, b, c, false);   // v_dot2_f32_f16
#else
    return fmaf((float)a.x, (float)b.x, fmaf((float)a.y, (float)b.y, c));
#endif
}

template<int CTRL>
__device__ __forceinline__ float dppadd(float v) {   // v + dpp_perm(v), VALU-only
    return v + __int_as_float(__builtin_amdgcn_update_dpp(
        0, __float_as_int(v), CTRL, 0xF, 0xF, true));
}

// ---------------------------------------------------------------------------
// prep: W[2048][32][8][16] f32 -> W16[i][j 8][l 64][d2 4] packed hf2 (16 MB).
// W16 float4 index for (i, j, l): i*512 + j*64 + l  (each (i,j) = 1 KB block).
// ---------------------------------------------------------------------------
__global__ __launch_bounds__(512)
void prep_kernel(const float* __restrict__ W, float* __restrict__ W16)
{
    const int ch = blockIdx.x;               // 256 blocks: 8 i's each
    const int t  = threadIdx.x;
    const int is = t >> 6, l = t & 63, o = l & 31, kk = l >> 5;
    const int i  = ch * 8 + is;

    const float* wp = W + (size_t)(i * 32 + o) * 128 + kk * 8;
    float r[8][8];
    #pragma unroll
    for (int d = 0; d < 8; ++d) {
        float4 a = *(const float4*)(wp + d * 16);
        float4 b = *(const float4*)(wp + d * 16 + 4);
        r[d][0] = a.x; r[d][1] = a.y; r[d][2] = a.z; r[d][3] = a.w;
        r[d][4] = b.x; r[d][5] = b.y; r[d][6] = b.z; r[d][7] = b.w;
    }
    float4* dst = (float4*)W16 + (size_t)i * 512 + l;
    #pragma unroll
    for (int j = 0; j < 8; ++j) {
        float o4[4];
        #pragma unroll
        for (int d2 = 0; d2 < 4; ++d2) {
            hf2 p; p.x = (_Float16)r[2 * d2][j]; p.y = (_Float16)r[2 * d2 + 1][j];
            o4[d2] = __builtin_bit_cast(float, p);
        }
        dst[(size_t)j * 64] = make_float4(o4[0], o4[1], o4[2], o4[3]);
    }
}

template<int PASS0>
__global__ __launch_bounds__(512, 6)   // budget 42 VGPR -> 3 blocks/CU target
void pass_kernel(const float* __restrict__ x,     // [64][2048][8]
                 const float* __restrict__ W16,   // packed (see prep)
                 const __half* __restrict__ vin,  // [64][512] fp16, o-major
                 __half* __restrict__ part)       // [64][256][512] fp16
{
    __shared__ __align__(16) hf2    x_ldsh[16][8][4];  //  2 KB: [bl][i][d-pair]
    __shared__ __align__(16) __half redh[2][16][512];  // 32 KB: [par][slot*2+bq][e]

    const int t  = threadIdx.x;
    const int w  = t >> 6;
    const int l  = t & 63;
    const int o  = l & 31;
    const int kk = l >> 5;
    const int bx = blockIdx.x;
    const int ch = bx & 255;
    const int qh = bx >> 8;          // b-quarter: b in [qh*16, qh*16+16)

    // ---- W16 -> 32 regs of packed fp16 d-pairs: 8 coalesced float4 loads ---
    float Whf[4][8];
    {
        const float4* wp = (const float4*)W16 + (size_t)(ch * 8 + w) * 512 + l;
        #pragma unroll
        for (int j = 0; j < 8; ++j) {
            float4 ld = wp[(size_t)j * 64];     // 1 KB contiguous per wave
            Whf[0][j] = ld.x; Whf[1][j] = ld.y; Whf[2][j] = ld.z; Whf[3][j] = ld.w;
        }
        #pragma unroll
        for (int d2 = 0; d2 < 4; ++d2)
            #pragma unroll
            for (int j = 0; j < 8; ++j)
                asm volatile("" : "+v"(Whf[d2][j]));   // force VGPR residency
    }
    // ---- stage x packed fp16: 512 hf2, one per thread ----------------------
    {
        const int bl = t >> 5, wv = (t >> 2) & 7, d2 = t & 3;
        const float2 xx = *(const float2*)(
            x + (size_t)(qh * 16 + bl) * 16384 + (size_t)(ch * 8 + wv) * 8 + 2 * d2);
        hf2 p; p.x = (_Float16)xx.x; p.y = (_Float16)xx.y;
        x_ldsh[bl][wv][d2] = p;
    }

    #pragma unroll 2
    for (int g = 0; g < 8; ++g) {        // 2 b's per group, 8 groups
        __syncthreads();                 // redh[g&1] free; g=0: x_ldsh ready

        // ---- fold(g-1): sum 8 i-slots of redh[(g-1)&1], write part (fp16) --
        if (g && t < 256) {
            const int bqf = t >> 7;
            const int hx  = (t & 127) * 4;           // half index in [0,512)
            const __half* rp = &redh[(g - 1) & 1][0][0];
            float a0 = 0.f, a1 = 0.f, a2 = 0.f, a3 = 0.f;
            #pragma unroll
            for (int s = 0; s < 8; ++s) {
                H4 v = *(const H4*)(rp + (s * 2 + bqf) * 512 + hx);
                float2 f0 = __half22float2(v.a), f1 = __half22float2(v.b);
                a0 += f0.x; a1 += f0.y; a2 += f1.x; a3 += f1.y;
            }
            const int b = qh * 16 + (g - 1) * 2 + bqf;
            H4 o4;
            o4.a = __floats2half2_rn(a0, a1);
            o4.b = __floats2half2_rn(a2, a3);
            *(H4*)(part + ((size_t)b * 256 + ch) * 512 + hx) = o4;
        }

        // ---- compute(g) -> redh[g&1] --------------------------------------
        #pragma unroll
        for (int bq = 0; bq < 2; ++bq) {
            const int bl = g * 2 + bq;
            H8 vv;                       // 4 VGPRs live across the dot2 loop
            if (!PASS0) {                // issue early (L1/L2 latency)
                vv = *(const H8*)(vin + (size_t)(qh * 16 + bl) * 512 + o * 16 + kk * 8);
            }
            // x for this (b, i): 4 packed d-pairs, one 16B broadcast read
            const hf2* xp = &x_ldsh[bl][w][0];
            hf2 xa0 = xp[0], xa1 = xp[1], xa2 = xp[2], xa3 = xp[3];
            float uh[8];
            #pragma unroll
            for (int j = 0; j < 8; ++j) uh[j] = 0.f;
            #pragma unroll
            for (int j = 0; j < 8; ++j) {
                uh[j] = dot2(xa0, __builtin_bit_cast(hf2, Whf[0][j]), uh[j]);
                uh[j] = dot2(xa1, __builtin_bit_cast(hf2, Whf[1][j]), uh[j]);
                uh[j] = dot2(xa2, __builtin_bit_cast(hf2, Whf[2][j]), uh[j]);
                uh[j] = dot2(xa3, __builtin_bit_cast(hf2, Whf[3][j]), uh[j]);
            }
            float c;
            if (PASS0) {
                c = 0.03125f;            // softmax of zeros
            } else {
                float2 v0 = __half22float2(vv.a), v1 = __half22float2(vv.b);
                float2 v2 = __half22float2(vv.c), v3 = __half22float2(vv.d);
                float logit = uh[0] * v0.x;
                logit = fmaf(uh[1], v0.y, logit);
                logit = fmaf(uh[2], v1.x, logit);
                logit = fmaf(uh[3], v1.y, logit);
                logit = fmaf(uh[4], v2.x, logit);
                logit = fmaf(uh[5], v2.y, logit);
                logit = fmaf(uh[6], v3.x, logit);
                logit = fmaf(uh[7], v3.y, logit);
                logit += __shfl_xor(logit, 32, 64);   // combine k-halves (1 DS)
                float ex = __expf(logit);             // |logit| small: no max
                float sm = ex;                        // o-sum: 4 DPP + xor16
                sm = dppadd<0xB1>(sm);                // quad_perm xor1
                sm = dppadd<0x4E>(sm);                // quad_perm xor2
                sm = dppadd<0x124>(sm);               // row_ror:4
                sm = dppadd<0x128>(sm);               // row_ror:8
                sm += __int_as_float(__builtin_amdgcn_ds_swizzle(
                          __float_as_int(sm), 0x401F));   // xor16 within 32
                c = __fdividef(ex, sm);
            }
            H8 pk;
            pk.a = __floats2half2_rn(c * uh[0], c * uh[1]);
            pk.b = __floats2half2_rn(c * uh[2], c * uh[3]);
            pk.c = __floats2half2_rn(c * uh[4], c * uh[5]);
            pk.d = __floats2half2_rn(c * uh[6], c * uh[7]);
            *(H8*)&redh[g & 1][w * 2 + bq][o * 16 + kk * 8] = pk;   // 1 b128
        }
    }
    __syncthreads();
    if (t < 256) {   // ---- epilogue fold(g=7) from redh[1] ------------------
        const int bqf = t >> 7;
        const int hx  = (t & 127) * 4;
        const __half* rp = &redh[1][0][0];
        float a0 = 0.f, a1 = 0.f, a2 = 0.f, a3 = 0.f;
        #pragma unroll
        for (int s = 0; s < 8; ++s) {
            H4 v = *(const H4*)(rp + (s * 2 + bqf) * 512 + hx);
            float2 f0 = __half22float2(v.a), f1 = __half22float2(v.b);
            a0 += f0.x; a1 += f0.y; a2 += f1.x; a3 += f1.y;
        }
        const int b = qh * 16 + 14 + bqf;
        H4 o4;
        o4.a = __floats2half2_rn(a0, a1);
        o4.b = __floats2half2_rn(a2, a3);
        *(H4*)(part + ((size_t)b * 256 + ch) * 512 + hx) = o4;
    }
}

// ---------------------------------------------------------------------------
// Reduce (round-4..10 proven structure; vsum now fp16).
// ---------------------------------------------------------------------------
template<int PHASE>
__global__ __launch_bounds__(1024)
void reduce_kernel(const __half* __restrict__ part,
                   __half* __restrict__ vsum,
                   float* __restrict__ out)
{
    __shared__ __align__(16) float sA[128][64];   // 32 KB
    __shared__ __align__(16) float sB[16][64];    //  4 KB
    const int bx = blockIdx.x;
    const int b  = bx >> 3;
    const int q  = bx & 7;
    const int t  = threadIdx.x;
    const int f  = t & 7;
    const int c0 = t >> 3;                        // chunk row in [0,128)

    const __half* p0 = part + ((size_t)b * 256 + c0) * 512 + q * 64 + f * 8;
    float acc[8] = {0.f, 0.f, 0.f, 0.f, 0.f, 0.f, 0.f, 0.f};
    #pragma unroll
    for (int rr = 0; rr < 2; ++rr) {              // rows c0, c0+128
        H8 v = *(const H8*)(p0 + (size_t)rr * 128 * 512);
        float2 f0 = __half22float2(v.a), f1 = __half22float2(v.b),
               f2 = __half22float2(v.c), f3 = __half22float2(v.d);
        acc[0] += f0.x; acc[1] += f0.y; acc[2] += f1.x; acc[3] += f1.y;
        acc[4] += f2.x; acc[5] += f2.y; acc[6] += f3.x; acc[7] += f3.y;
    }
    *(float4*)&sA[c0][f * 8]     = make_float4(acc[0], acc[1], acc[2], acc[3]);
    *(float4*)&sA[c0][f * 8 + 4] = make_float4(acc[4], acc[5], acc[6], acc[7]);
    __syncthreads();

    {                                             // 128 rows -> 16
        const int e = t & 63, r4 = t >> 6;        // r4 in [0,16)
        float sb = 0.f;
        #pragma unroll
        for (int k2 = 0; k2 < 8; ++k2) sb += sA[r4 + k2 * 16][e];
        sB[r4][e] = sb;
    }
    __syncthreads();

    if (t < 64) {                                 // one wave: 16 rows, squash
        float s1 = 0.f;
        #pragma unroll
        for (int r = 0; r < 16; ++r) s1 += sB[r][t];
        float sq = s1 * s1;
        #pragma unroll
        for (int off = 8; off >= 1; off >>= 1)
            sq += __shfl_xor(sq, off, 16);        // sum over 16 k within o
        float v = (sq / (1.f + sq) * rsqrtf(sq + 1e-7f)) * s1;
        const size_t idx = (size_t)b * 512 + q * 64 + t;
        if (PHASE == 2)      out[idx] = v;        // e = o*16+k == [b][o][k]
        else if (PHASE == 1) vsum[idx] = __float2half((float)vsum[idx] + v);
        else                 vsum[idx] = __float2half(v);
    }
}

// ---------------------------------------------------------------------------
extern "C" void kernel_launch(void* const* d_in, const int* in_sizes, int n_in,
                              void* d_out, int out_size, void* d_ws, size_t ws_size,
                              hipStream_t stream)
{
    const float* x = (const float*)d_in[0];
    const float* W = (const float*)d_in[1];
    float* out = (float*)d_out;
    char* ws = (char*)d_ws;

    const size_t partB = (size_t)64 * 256 * 512 * 2;        // 16 MB (fp16)
    const size_t vsumB = (size_t)64 * 512 * 2;              // 64 KB (fp16)
    const size_t w16B  = (size_t)2048 * 32 * 8 * 16 * 2;    // 16 MB (fp16)
    if (ws_size < partB + vsumB + w16B) return;

    __half* part = (__half*)ws;
    __half* vsum = (__half*)(ws + partB);
    float*  W16  = (float*)(ws + partB + vsumB);

    // one-time W repack (must rerun every launch: ws may be re-poisoned)
    prep_kernel<<<256, 512, 0, stream>>>(W, W16);

    // round 0: c uniform -> v0; vsum = v0
    pass_kernel<1><<<1024, 512, 0, stream>>>(x, W16, vsum, part);
    reduce_kernel<0><<<512, 1024, 0, stream>>>(part, vsum, out);
    // round 1: logits = u_hat . v0 -> v1; vsum = v0 + v1
    pass_kernel<0><<<1024, 512, 0, stream>>>(x, W16, vsum, part);
    reduce_kernel<1><<<512, 1024, 0, stream>>>(part, vsum, out);
    // round 2: logits = u_hat . (v0+v1) -> v2 = output
    pass_kernel<0><<<1024, 512, 0, stream>>>(x, W16, vsum, part);
    reduce_kernel<2><<<512, 1024, 0, stream>>>(part, vsum, out);
}

// Round 12
// 174.691 us; speedup vs baseline: 1.0931x; 1.0105x over previous
//
#include <hip/hip_runtime.h>
#include <hip/hip_fp16.h>

// B=64, I=2048, D=8, O=32, K=16.  e-layout o-major: e = o*16 + k.
//
// Round-12: memory-side fixes (pass floor responds only to memory changes).
// part relayout [64][8 q][256 ch][64 r] (same 16 MB fp16):
//  - pass fold: each 16-thread group writes one FULL 128-B line (aligned)
//    -> no L2 write-allocate (r7/r8 FETCH showed ~16 MB of read-for-write).
//  - reduce: each (b,q) slice is 32 KB CONTIGUOUS -> wave reads 2 KB/instr
//    (was 8 scattered 64-B segments @1KB stride, 2.1 TB/s). New 3-stage
//    LDS fold, same squash tail.
// Pass compute core, prep/W16, vsum fp16: round-11 verbatim.
//
// grid 1024 = (qh = bx>>8: b-quarter, 16 b's) x (ch = bx&255: 8-i chunk).
// wave w = i-slot; lane: o = l&31, kk = l>>5.

typedef _Float16 hf2 __attribute__((ext_vector_type(2)));

struct __align__(16) H8 { __half2 a, b, c, d; };
struct __align__(8)  H4 { __half2 a, b; };

__device__ __forceinline__ float dot2(hf2 a, hf2 b, float c) {
#if __has_builtin(__builtin_amdgcn_fdot2)
    return __builtin_amdgcn_fdot2(a, b, c, false);   // v_dot2_f32_f16
#else
    return fmaf((float)a.x, (float)b.x, fmaf((float)a.y, (float)b.y, c));
#endif
}

template<int CTRL>
__device__ __forceinline__ float dppadd(float v) {   // v + dpp_perm(v), VALU-only
    return v + __int_as_float(__builtin_amdgcn_update_dpp(
        0, __float_as_int(v), CTRL, 0xF, 0xF, true));
}

// ---------------------------------------------------------------------------
// prep: W[2048][32][8][16] f32 -> W16[i][j 8][l 64][d2 4] packed hf2 (16 MB).
// ---------------------------------------------------------------------------
__global__ __launch_bounds__(512)
void prep_kernel(const float* __restrict__ W, float* __restrict__ W16)
{
    const int ch = blockIdx.x;               // 256 blocks: 8 i's each
    const int t  = threadIdx.x;
    const int is = t >> 6, l = t & 63, o = l & 31, kk = l >> 5;
    const int i  = ch * 8 + is;

    const float* wp = W + (size_t)(i * 32 + o) * 128 + kk * 8;
    float r[8][8];
    #pragma unroll
    for (int d = 0; d < 8; ++d) {
        float4 a = *(const float4*)(wp + d * 16);
        float4 b = *(const float4*)(wp + d * 16 + 4);
        r[d][0] = a.x; r[d][1] = a.y; r[d][2] = a.z; r[d][3] = a.w;
        r[d][4] = b.x; r[d][5] = b.y; r[d][6] = b.z; r[d][7] = b.w;
    }
    float4* dst = (float4*)W16 + (size_t)i * 512 + l;
    #pragma unroll
    for (int j = 0; j < 8; ++j) {
        float o4[4];
        #pragma unroll
        for (int d2 = 0; d2 < 4; ++d2) {
            hf2 p; p.x = (_Float16)r[2 * d2][j]; p.y = (_Float16)r[2 * d2 + 1][j];
            o4[d2] = __builtin_bit_cast(float, p);
        }
        dst[(size_t)j * 64] = make_float4(o4[0], o4[1], o4[2], o4[3]);
    }
}

template<int PASS0>
__global__ __launch_bounds__(512, 6)   // budget 42 VGPR, r11-proven
void pass_kernel(const float* __restrict__ x,     // [64][2048][8]
                 const float* __restrict__ W16,   // packed (see prep)
                 const __half* __restrict__ vin,  // [64][512] fp16, o-major
                 __half* __restrict__ part)       // [64][8][256][64] fp16
{
    __shared__ __align__(16) hf2    x_ldsh[16][8][4];  //  2 KB: [bl][i][d-pair]
    __shared__ __align__(16) __half redh[2][16][512];  // 32 KB: [par][slot*2+bq][e]

    const int t  = threadIdx.x;
    const int w  = t >> 6;
    const int l  = t & 63;
    const int o  = l & 31;
    const int kk = l >> 5;
    const int bx = blockIdx.x;
    const int ch = bx & 255;
    const int qh = bx >> 8;          // b-quarter: b in [qh*16, qh*16+16)

    // ---- W16 -> 32 regs of packed fp16 d-pairs: 8 coalesced float4 loads ---
    float Whf[4][8];
    {
        const float4* wp = (const float4*)W16 + (size_t)(ch * 8 + w) * 512 + l;
        #pragma unroll
        for (int j = 0; j < 8; ++j) {
            float4 ld = wp[(size_t)j * 64];     // 1 KB contiguous per wave
            Whf[0][j] = ld.x; Whf[1][j] = ld.y; Whf[2][j] = ld.z; Whf[3][j] = ld.w;
        }
        #pragma unroll
        for (int d2 = 0; d2 < 4; ++d2)
            #pragma unroll
            for (int j = 0; j < 8; ++j)
                asm volatile("" : "+v"(Whf[d2][j]));   // force VGPR residency
    }
    // ---- stage x packed fp16: 512 hf2, one per thread ----------------------
    {
        const int bl = t >> 5, wv = (t >> 2) & 7, d2 = t & 3;
        const float2 xx = *(const float2*)(
            x + (size_t)(qh * 16 + bl) * 16384 + (size_t)(ch * 8 + wv) * 8 + 2 * d2);
        hf2 p; p.x = (_Float16)xx.x; p.y = (_Float16)xx.y;
        x_ldsh[bl][wv][d2] = p;
    }

    #pragma unroll 2
    for (int g = 0; g < 8; ++g) {        // 2 b's per group, 8 groups
        __syncthreads();                 // redh[g&1] free; g=0: x_ldsh ready

        // ---- fold(g-1): sum 8 i-slots of redh[(g-1)&1] -> part -------------
        // new layout: 16 consecutive threads (same q) write one 128-B line
        if (g && t < 256) {
            const int bqf = t >> 7;
            const int hx  = (t & 127) * 4;           // half index in [0,512)
            const __half* rp = &redh[(g - 1) & 1][0][0];
            float a0 = 0.f, a1 = 0.f, a2 = 0.f, a3 = 0.f;
            #pragma unroll
            for (int s = 0; s < 8; ++s) {
                H4 v = *(const H4*)(rp + (s * 2 + bqf) * 512 + hx);
                float2 f0 = __half22float2(v.a), f1 = __half22float2(v.b);
                a0 += f0.x; a1 += f0.y; a2 += f1.x; a3 += f1.y;
            }
            const int b = qh * 16 + (g - 1) * 2 + bqf;
            const int qq = hx >> 6, rr = hx & 63;
            H4 o4;
            o4.a = __floats2half2_rn(a0, a1);
            o4.b = __floats2half2_rn(a2, a3);
            *(H4*)(part + (((size_t)b * 8 + qq) * 256 + ch) * 64 + rr) = o4;
        }

        // ---- compute(g) -> redh[g&1] --------------------------------------
        #pragma unroll
        for (int bq = 0; bq < 2; ++bq) {
            const int bl = g * 2 + bq;
            H8 vv;                       // 4 VGPRs live across the dot2 loop
            if (!PASS0) {                // issue early (L1/L2 latency)
                vv = *(const H8*)(vin + (size_t)(qh * 16 + bl) * 512 + o * 16 + kk * 8);
            }
            const hf2* xp = &x_ldsh[bl][w][0];
            hf2 xa0 = xp[0], xa1 = xp[1], xa2 = xp[2], xa3 = xp[3];
            float uh[8];
            #pragma unroll
            for (int j = 0; j < 8; ++j) uh[j] = 0.f;
            #pragma unroll
            for (int j = 0; j < 8; ++j) {
                uh[j] = dot2(xa0, __builtin_bit_cast(hf2, Whf[0][j]), uh[j]);
                uh[j] = dot2(xa1, __builtin_bit_cast(hf2, Whf[1][j]), uh[j]);
                uh[j] = dot2(xa2, __builtin_bit_cast(hf2, Whf[2][j]), uh[j]);
                uh[j] = dot2(xa3, __builtin_bit_cast(hf2, Whf[3][j]), uh[j]);
            }
            float c;
            if (PASS0) {
                c = 0.03125f;            // softmax of zeros
            } else {
                float2 v0 = __half22float2(vv.a), v1 = __half22float2(vv.b);
                float2 v2 = __half22float2(vv.c), v3 = __half22float2(vv.d);
                float logit = uh[0] * v0.x;
                logit = fmaf(uh[1], v0.y, logit);
                logit = fmaf(uh[2], v1.x, logit);
                logit = fmaf(uh[3], v1.y, logit);
                logit = fmaf(uh[4], v2.x, logit);
                logit = fmaf(uh[5], v2.y, logit);
                logit = fmaf(uh[6], v3.x, logit);
                logit = fmaf(uh[7], v3.y, logit);
                logit += __shfl_xor(logit, 32, 64);   // combine k-halves (1 DS)
                float ex = __expf(logit);             // |logit| small: no max
                float sm = ex;                        // o-sum: 4 DPP + xor16
                sm = dppadd<0xB1>(sm);                // quad_perm xor1
                sm = dppadd<0x4E>(sm);                // quad_perm xor2
                sm = dppadd<0x124>(sm);               // row_ror:4
                sm = dppadd<0x128>(sm);               // row_ror:8
                sm += __int_as_float(__builtin_amdgcn_ds_swizzle(
                          __float_as_int(sm), 0x401F));   // xor16 within 32
                c = __fdividef(ex, sm);
            }
            H8 pk;
            pk.a = __floats2half2_rn(c * uh[0], c * uh[1]);
            pk.b = __floats2half2_rn(c * uh[2], c * uh[3]);
            pk.c = __floats2half2_rn(c * uh[4], c * uh[5]);
            pk.d = __floats2half2_rn(c * uh[6], c * uh[7]);
            *(H8*)&redh[g & 1][w * 2 + bq][o * 16 + kk * 8] = pk;   // 1 b128
        }
    }
    __syncthreads();
    if (t < 256) {   // ---- epilogue fold(g=7) from redh[1] ------------------
        const int bqf = t >> 7;
        const int hx  = (t & 127) * 4;
        const __half* rp = &redh[1][0][0];
        float a0 = 0.f, a1 = 0.f, a2 = 0.f, a3 = 0.f;
        #pragma unroll
        for (int s = 0; s < 8; ++s) {
            H4 v = *(const H4*)(rp + (s * 2 + bqf) * 512 + hx);
            float2 f0 = __half22float2(v.a), f1 = __half22float2(v.b);
            a0 += f0.x; a1 += f0.y; a2 += f1.x; a3 += f1.y;
        }
        const int b = qh * 16 + 14 + bqf;
        const int qq = hx >> 6, rr = hx & 63;
        H4 o4;
        o4.a = __floats2half2_rn(a0, a1);
        o4.b = __floats2half2_rn(a2, a3);
        *(H4*)(part + (((size_t)b * 8 + qq) * 256 + ch) * 64 + rr) = o4;
    }
}

// ---------------------------------------------------------------------------
// Reduce v2: grid 512 = (b = bx>>3) x (q = bx&7). Slice part[b][q] = 32 KB
// CONTIGUOUS (256 ch x 64 r halves). 1024 threads: thread t loads halves
// [t*16, t*16+16) (wave = 2 KB contiguous) -> ch = t>>2, r0 = (t&3)*16.
// 3-stage LDS fold (sAf padded +4 f32 vs stride-64 banks), squash tail.
// PHASE 0: vsum=v; 1: vsum+=v; 2: out[b][o][k]=v.
// ---------------------------------------------------------------------------
template<int PHASE>
__global__ __launch_bounds__(1024)
void reduce_kernel(const __half* __restrict__ part,
                   __half* __restrict__ vsum,
                   float* __restrict__ out)
{
    __shared__ float sAf[256][68];                // 69.6 KB (padded)
    __shared__ float sB[16][64];                  //  4 KB
    const int bx = blockIdx.x;
    const int b  = bx >> 3;
    const int q  = bx & 7;
    const int t  = threadIdx.x;

    const __half* base = part + (((size_t)b * 8 + q) * 256) * 64;  // 16384 halves
    H8 v0 = *(const H8*)(base + t * 16);          // 2 x 16 B, contiguous
    H8 v1 = *(const H8*)(base + t * 16 + 8);
    const int ch = t >> 2, rq = t & 3;
    float* dst = &sAf[ch][rq * 16];
    {
        float2 f;
        f = __half22float2(v0.a); dst[0]  = f.x; dst[1]  = f.y;
        f = __half22float2(v0.b); dst[2]  = f.x; dst[3]  = f.y;
        f = __half22float2(v0.c); dst[4]  = f.x; dst[5]  = f.y;
        f = __half22float2(v0.d); dst[6]  = f.x; dst[7]  = f.y;
        f = __half22float2(v1.a); dst[8]  = f.x; dst[9]  = f.y;
        f = __half22float2(v1.b); dst[10] = f.x; dst[11] = f.y;
        f = __half22float2(v1.c); dst[12] = f.x; dst[13] = f.y;
        f = __half22float2(v1.d); dst[14] = f.x; dst[15] = f.y;
    }
    __syncthreads();

    {                                             // 256 ch -> 16 groups
        const int grp = t >> 6, r = t & 63;
        float sb = 0.f;
        #pragma unroll
        for (int cc = 0; cc < 16; ++cc)
            sb += sAf[grp * 16 + cc][r];
        sB[grp][r] = sb;
    }
    __syncthreads();

    if (t < 64) {                                 // one wave: 16 rows, squash
        float s1 = 0.f;
        #pragma unroll
        for (int grp = 0; grp < 16; ++grp) s1 += sB[grp][t];
        float sq = s1 * s1;
        #pragma unroll
        for (int off = 8; off >= 1; off >>= 1)
            sq += __shfl_xor(sq, off, 16);        // sum over 16 k within o
        float v = (sq / (1.f + sq) * rsqrtf(sq + 1e-7f)) * s1;
        const size_t idx = (size_t)b * 512 + q * 64 + t;
        if (PHASE == 2)      out[idx] = v;        // e = o*16+k == [b][o][k]
        else if (PHASE == 1) vsum[idx] = __float2half((float)vsum[idx] + v);
        else                 vsum[idx] = __float2half(v);
    }
}

// ---------------------------------------------------------------------------
extern "C" void kernel_launch(void* const* d_in, const int* in_sizes, int n_in,
                              void* d_out, int out_size, void* d_ws, size_t ws_size,
                              hipStream_t stream)
{
    const float* x = (const float*)d_in[0];
    const float* W = (const float*)d_in[1];
    float* out = (float*)d_out;
    char* ws = (char*)d_ws;

    const size_t partB = (size_t)64 * 8 * 256 * 64 * 2;     // 16 MB (fp16)
    const size_t vsumB = (size_t)64 * 512 * 2;              // 64 KB (fp16)
    const size_t w16B  = (size_t)2048 * 32 * 8 * 16 * 2;    // 16 MB (fp16)
    if (ws_size < partB + vsumB + w16B) return;             // <= proven 33.69 MB

    __half* part = (__half*)ws;
    __half* vsum = (__half*)(ws + partB);
    float*  W16  = (float*)(ws + partB + vsumB);

    // one-time W repack (must rerun every launch: ws may be re-poisoned)
    prep_kernel<<<256, 512, 0, stream>>>(W, W16);

    // round 0: c uniform -> v0; vsum = v0
    pass_kernel<1><<<1024, 512, 0, stream>>>(x, W16, vsum, part);
    reduce_kernel<0><<<512, 1024, 0, stream>>>(part, vsum, out);
    // round 1: logits = u_hat . v0 -> v1; vsum = v0 + v1
    pass_kernel<0><<<1024, 512, 0, stream>>>(x, W16, vsum, part);
    reduce_kernel<1><<<512, 1024, 0, stream>>>(part, vsum, out);
    // round 2: logits = u_hat . (v0+v1) -> v2 = output
    pass_kernel<0><<<1024, 512, 0, stream>>>(x, W16, vsum, part);
    reduce_kernel<2><<<512, 1024, 0, stream>>>(part, vsum, out);
}